// Round 15
// baseline (417.212 us; speedup 1.0000x reference)
//
#include <hip/hip_runtime.h>
#include <math.h>

typedef __attribute__((ext_vector_type(8))) short short8;
typedef __attribute__((ext_vector_type(4))) float f32x4;
typedef __attribute__((ext_vector_type(2))) unsigned int u32x2;
typedef __attribute__((ext_vector_type(4))) unsigned int u32x4;

#define E_NUM 16
constexpr int CAPS[E_NUM] = {1024,512,1024,256,1024,512,128,1024,512,1024,256,512,1024,128,64,512};
constexpr int OFFS[E_NUM] = {0,1024,1536,2560,2816,3840,4352,4480,5504,6016,7040,7296,7808,8832,8960,9024};
constexpr int cdiv_(int a, int b){ return (a + b - 1) / b; }
constexpr int ilog2_(int v){ int l = 0; while ((1 << l) < v) ++l; return l; }

__device__ __forceinline__ unsigned int cvt_pk_bf16(float a, float b){
  unsigned int r;
  asm("v_cvt_pk_bf16_f32 %0, %1, %2" : "=v"(r) : "v"(a), "v"(b));
  return r;
}

typedef __attribute__((address_space(1))) const unsigned char gas_u8;
typedef __attribute__((address_space(3))) unsigned char las_u8;
__device__ __forceinline__ void gl_lds16(const void* g, void* l){
  __builtin_amdgcn_global_load_lds((gas_u8*)g, (las_u8*)l, 16, 0, 0);
}

// fp32 -> bf16 (RNE), 8 elems/thread, grid-stride (used for x)
__global__ __launch_bounds__(256) void cvt_bf16_kernel(const float* __restrict__ x,
                                                       unsigned short* __restrict__ xb, int n8)
{
  int i = blockIdx.x * blockDim.x + threadIdx.x;
  const int stride = gridDim.x * blockDim.x;
  for (; i < n8; i += stride) {
    f32x4 a = *reinterpret_cast<const f32x4*>(x + (size_t)i * 8);
    f32x4 b = *reinterpret_cast<const f32x4*>(x + (size_t)i * 8 + 4);
    u32x2 lo, hi;
    lo[0] = cvt_pk_bf16(a[0], a[1]); lo[1] = cvt_pk_bf16(a[2], a[3]);
    hi[0] = cvt_pk_bf16(b[0], b[1]); hi[1] = cvt_pk_bf16(b[2], b[3]);
    *reinterpret_cast<u32x2*>(xb + (size_t)i * 8)     = lo;
    *reinterpret_cast<u32x2*>(xb + (size_t)i * 8 + 4) = hi;
  }
}

// ============ G1 body: 256x256, 3-buf counted-vmcnt, bf16-A glds + fp32-B glds ========
// (verbatim R8-proven structure; device-inlined so it can share a kernel with W2-cvt)
template<int NDIM, int KDIM, int LOG_GN, int NWG>
__device__ __forceinline__ void g1_body(int braw, const unsigned short* __restrict__ Ah,
                                        const float* __restrict__ W,
                                        const float* __restrict__ bias,
                                        unsigned short* __restrict__ Oh, char* smem)
{
  constexpr int A_BYTES = 256 * 64;
  constexpr int B_BYTES = 256 * 128;
  constexpr int BUF  = A_BYTES + B_BYTES;   // 48 KB
  constexpr int GN   = 1 << LOG_GN;
  constexpr int NTT  = KDIM / 32;
  static_assert(NWG % 8 == 0);
  static_assert(NTT >= 3);

  const int tid = threadIdx.x;
  const int tt = (braw & 7) * (NWG / 8) + (braw >> 3);

  int m0 = 0, n0 = 0, Me = 0, tok0 = 0;
  size_t wbase = 0, bbase = 0;
  {
    int acc0 = 0;
    #pragma unroll
    for (int i = 0; i < E_NUM; ++i) {
      const int mt  = cdiv_(CAPS[i], 256);
      const int lmt = ilog2_(mt);
      const int nb  = mt * (NDIM / 256);
      if (tt >= acc0 && tt < acc0 + nb) {
        const int loc = tt - acc0;
        const int g   = loc >> (lmt + LOG_GN);
        const int rem = loc & ((mt << LOG_GN) - 1);
        m0   = (rem >> LOG_GN) * 256;
        n0   = ((g << LOG_GN) | (rem & (GN - 1))) * 256;
        Me   = CAPS[i];
        tok0 = OFFS[i];
        wbase = (size_t)i * NDIM * KDIM;
        bbase = (size_t)i * NDIM;
      }
      acc0 += nb;
    }
  }
  const float* Wb = W + wbase;

  const int lane = tid & 63;
  const int wv   = tid >> 6;

  auto stageA = [&](int buf, int kt) {
    const unsigned short* Ag = Ah + (size_t)(tok0 + m0) * KDIM + kt * 32;
    char* dst0 = smem + buf * BUF;
    #pragma unroll
    for (int j = 0; j < 2; ++j) {
      const int rbase = j * 128 + wv * 16;
      const int r     = rbase + (lane >> 2);
      const int blk   = (lane & 3) ^ (r & 3);
      gl_lds16((const void*)(Ag + (size_t)r * KDIM + blk * 8), (void*)(dst0 + rbase * 64));
    }
  };
  auto stageB = [&](int buf, int kt) {
    const float* Bg = Wb + (size_t)n0 * KDIM + kt * 32;
    char* dst0 = smem + buf * BUF + A_BYTES;
    #pragma unroll
    for (int j = 0; j < 4; ++j) {
      const int rbase = j * 64 + wv * 8;
      const int r     = rbase + (lane >> 3);
      const int blk   = (lane & 7) ^ (r & 7);
      gl_lds16((const void*)(Bg + (size_t)r * KDIM + blk * 4), (void*)(dst0 + rbase * 128));
    }
  };

  const int wm   = (wv >> 2) * 128;
  const int wn   = (wv & 3) * 64;
  const int lrow = lane & 15;
  const int pa0  = (((lane >> 4) ^ (lane & 3)) << 4);
  const int pb0  = ((((lane >> 4) << 1) ^ (lane & 7)) << 4);

  f32x4 acc_[8][4];
  #pragma unroll
  for (int i = 0; i < 8; ++i)
    #pragma unroll
    for (int j = 0; j < 4; ++j)
      acc_[i][j] = (f32x4){0.f, 0.f, 0.f, 0.f};

  auto compute = [&](int cur) {
    const char* ab  = smem + cur * BUF;
    const char* bbp = smem + cur * BUF + A_BYTES;
    short8 bfr[4];
    #pragma unroll
    for (int f = 0; f < 4; ++f) {
      const char* rowp = bbp + (size_t)(wn + f * 16 + lrow) * 128;
      f32x4 lo = *reinterpret_cast<const f32x4*>(rowp + pb0);
      f32x4 hi = *reinterpret_cast<const f32x4*>(rowp + (pb0 ^ 16));
      u32x4 pk;
      pk[0] = cvt_pk_bf16(lo[0], lo[1]); pk[1] = cvt_pk_bf16(lo[2], lo[3]);
      pk[2] = cvt_pk_bf16(hi[0], hi[1]); pk[3] = cvt_pk_bf16(hi[2], hi[3]);
      bfr[f] = __builtin_bit_cast(short8, pk);
    }
    #pragma unroll
    for (int i = 0; i < 8; ++i) {
      short8 afr = *reinterpret_cast<const short8*>(ab + (wm + i * 16 + lrow) * 64 + pa0);
      #pragma unroll
      for (int j = 0; j < 4; ++j)
        acc_[i][j] = __builtin_amdgcn_mfma_f32_16x16x32_bf16(afr, bfr[j], acc_[i][j], 0, 0, 0);
    }
  };

  stageA(0, 0); stageB(0, 0);
  stageA(1, 1); stageB(1, 1);
  int cur = 0, nx2 = 2;
  for (int kt = 0; kt < NTT; ++kt) {
    if (kt + 1 < NTT) asm volatile("s_waitcnt vmcnt(6)\n\ts_barrier" ::: "memory");
    else              asm volatile("s_waitcnt vmcnt(0)\n\ts_barrier" ::: "memory");
    __builtin_amdgcn_sched_barrier(0);
    if (kt + 2 < NTT) { stageA(nx2, kt + 2); stageB(nx2, kt + 2); }
    compute(cur);
    cur = (cur == 2) ? 0 : cur + 1;
    nx2 = (nx2 == 2) ? 0 : nx2 + 1;
  }

  float bv[4];
  #pragma unroll
  for (int f = 0; f < 4; ++f)
    bv[f] = bias[bbase + n0 + wn + f * 16 + lrow];

  __syncthreads();
  unsigned short* hout = (unsigned short*)smem;   // 128 KB scratch
  #pragma unroll
  for (int i = 0; i < 8; ++i) {
    const int rbase = wm + i * 16 + (lane >> 4) * 4;
    #pragma unroll
    for (int j = 0; j < 4; ++j) {
      #pragma unroll
      for (int jj = 0; jj < 4; ++jj) {
        float xv = acc_[i][j][jj] + bv[j];
        float y2 = xv * (1.5957691216057308f + 0.07135481627f * xv * xv);
        float g  = xv * __builtin_amdgcn_rcpf(1.0f + __expf(-y2));
        hout[(rbase + jj) * 256 + wn + j * 16 + lrow] = (unsigned short)(cvt_pk_bf16(g, g) & 0xFFFFu);
      }
    }
  }
  __syncthreads();
  #pragma unroll
  for (int s = 0; s < 16; ++s) {
    const int row = s * 16 + (tid >> 5);
    const int c   = (tid & 31) * 8;
    if (m0 + row < Me) {
      *reinterpret_cast<short8*>(Oh + (size_t)(tok0 + m0 + row) * NDIM + n0 + c)
        = *reinterpret_cast<const short8*>(hout + row * 256 + c);
    }
  }
}

// ======= merged kernel: blocks [0,G1_NWG) = G1; rest convert W2 fp32->bf16 =========
// cvt blocks are dispatched after G1 blocks, so they backfill the G1 tail round and
// drain — W2's ~400 MB conversion rides G1's idle HBM BW. vmcnt is per-wave, so the
// cvt path cannot perturb G1's counted waits. G2 (next launch) sees completed w2b.
constexpr int G1_NWG  = 624;
constexpr int CVT_NWG = 640;

__global__ __launch_bounds__(512, 2)
void g1cvt(const unsigned short* __restrict__ xb, const float* __restrict__ W1,
           const float* __restrict__ b1, unsigned short* __restrict__ h,
           const float* __restrict__ W2, unsigned short* __restrict__ w2b)
{
  __shared__ __align__(16) char smem[3 * (256 * 64 + 256 * 128)];   // 144 KB
  if ((int)blockIdx.x < G1_NWG) {
    g1_body<4096, 1024, 2, G1_NWG>(blockIdx.x, xb, W1, b1, h, smem);
  } else {
    constexpr int N8 = 16 * 1024 * 4096 / 8;
    int i = ((int)blockIdx.x - G1_NWG) * 512 + (int)threadIdx.x;
    const int stride = CVT_NWG * 512;
    for (; i < N8; i += stride) {
      f32x4 a = *reinterpret_cast<const f32x4*>(W2 + (size_t)i * 8);
      f32x4 b = *reinterpret_cast<const f32x4*>(W2 + (size_t)i * 8 + 4);
      u32x2 lo, hi;
      lo[0] = cvt_pk_bf16(a[0], a[1]); lo[1] = cvt_pk_bf16(a[2], a[3]);
      hi[0] = cvt_pk_bf16(b[0], b[1]); hi[1] = cvt_pk_bf16(b[2], b[3]);
      *reinterpret_cast<u32x2*>(w2b + (size_t)i * 8)     = lo;
      *reinterpret_cast<u32x2*>(w2b + (size_t)i * 8 + 4) = hi;
    }
  }
}

// ============ G2: 256x256, 512 thr, PURE-bf16, 3-buf counted vmcnt(4), KS=4 =========
// out += h @ w2b^T + b2/KS.  A (h) and B (w2b) both bf16 via gl_lds: 2+2 gl_lds16
// per thread per tile, 32 KB/buffer, 3 bufs = 96 KB -> 1 block/CU (8 waves).
// Per wave-iter: 12 b128 LDS reads vs 32 MFMA — LDS-balanced (the HK 256² regime).
// launch_bounds(512,1): VGPR cap 256 (acc 128 + addressing ~60 fits; R11's cap-128
// spill trap avoided). Swizzle: phys_blk = blk ^ (r&3), src pre-swizzled.
template<int NDIM, int KDIM, int NWG, int KS>
__global__ __launch_bounds__(512, 1)
void g2_gemm256b(const unsigned short* __restrict__ Ah, const unsigned short* __restrict__ Wh,
                 const float* __restrict__ bias, float* __restrict__ Of)
{
  constexpr int T_BYTES = 256 * 64;          // one bf16 256x32 tile = 16 KB
  constexpr int BUF  = 2 * T_BYTES;          // A + B = 32 KB
  constexpr int NT   = KDIM / (KS * 32);
  constexpr int NWG1 = NWG / KS;
  static_assert(NWG % 8 == 0);
  static_assert(NT >= 3);

  __shared__ __align__(16) char smem[3 * BUF];   // 96 KB

  const int tid  = threadIdx.x;
  const int braw = blockIdx.x;
  const int t = (braw & 7) * (NWG / 8) + (braw >> 3);

  const int kc    = t / NWG1;
  const int tt    = t % NWG1;
  const int kbase = kc * (KDIM / KS);

  // m-fastest: all m-tiles of an expert walk one 256-col W2 panel before advancing n
  int m0 = 0, n0 = 0, Me = 0, tok0 = 0;
  size_t wbase = 0, bbase = 0;
  {
    int acc0 = 0;
    #pragma unroll
    for (int i = 0; i < E_NUM; ++i) {
      const int mt = cdiv_(CAPS[i], 256);        // 1,2,4 (pow2)
      const int nb = mt * (NDIM / 256);
      if (tt >= acc0 && tt < acc0 + nb) {
        const int loc = tt - acc0;
        m0   = (loc & (mt - 1)) * 256;
        n0   = (loc >> ilog2_(mt)) * 256;
        Me   = CAPS[i];
        tok0 = OFFS[i];
        wbase = (size_t)i * NDIM * KDIM;
        bbase = (size_t)i * NDIM;
      }
      acc0 += nb;
    }
  }

  const int lane = tid & 63;
  const int wv   = tid >> 6;            // 0..7

  const unsigned short* Abase = Ah + (size_t)(tok0 + m0) * KDIM + kbase;
  const unsigned short* Bbase = Wh + wbase + (size_t)n0 * KDIM + kbase;

  // stage one bf16 256x32 tile: 2 gl_lds16/thread (16 rows x 64B per inst per wave)
  auto stage_tile = [&](const unsigned short* base, char* dst0, int kt) {
    const unsigned short* Tg = base + kt * 32;
    #pragma unroll
    for (int j = 0; j < 2; ++j) {
      const int rbase = wv * 32 + j * 16;
      const int r     = rbase + (lane >> 2);
      const int blk   = (lane & 3) ^ (r & 3);
      gl_lds16((const void*)(Tg + (size_t)r * KDIM + blk * 8), (void*)(dst0 + rbase * 64));
    }
  };
  auto stage = [&](int buf, int kt) {
    stage_tile(Abase, smem + buf * BUF, kt);
    stage_tile(Bbase, smem + buf * BUF + T_BYTES, kt);
  };

  const int wm   = (wv >> 2) * 128;
  const int wn   = (wv & 3) * 64;
  const int lrow = lane & 15;
  const int pa0  = (((lane >> 4) ^ (lane & 3)) << 4);

  f32x4 acc_[8][4];
  #pragma unroll
  for (int i = 0; i < 8; ++i)
    #pragma unroll
    for (int j = 0; j < 4; ++j)
      acc_[i][j] = (f32x4){0.f, 0.f, 0.f, 0.f};

  auto compute = [&](int cur) {
    const char* ab = smem + cur * BUF;
    const char* bb = smem + cur * BUF + T_BYTES;
    short8 bfr[4];
    #pragma unroll
    for (int f = 0; f < 4; ++f)
      bfr[f] = *reinterpret_cast<const short8*>(bb + (wn + f * 16 + lrow) * 64 + pa0);
    #pragma unroll
    for (int i = 0; i < 8; ++i) {
      short8 afr = *reinterpret_cast<const short8*>(ab + (wm + i * 16 + lrow) * 64 + pa0);
      #pragma unroll
      for (int j = 0; j < 4; ++j)
        acc_[i][j] = __builtin_amdgcn_mfma_f32_16x16x32_bf16(afr, bfr[j], acc_[i][j], 0, 0, 0);
    }
  };

  stage(0, 0);
  stage(1, 1);
  int cur = 0, nx2 = 2;
  for (int kt = 0; kt < NT; ++kt) {
    if (kt + 1 < NT) asm volatile("s_waitcnt vmcnt(4)\n\ts_barrier" ::: "memory");
    else             asm volatile("s_waitcnt vmcnt(0)\n\ts_barrier" ::: "memory");
    __builtin_amdgcn_sched_barrier(0);
    if (kt + 2 < NT) stage(nx2, kt + 2);
    compute(cur);
    cur = (cur == 2) ? 0 : cur + 1;
    nx2 = (nx2 == 2) ? 0 : nx2 + 1;
  }

  float bv[4];
  #pragma unroll
  for (int f = 0; f < 4; ++f)
    bv[f] = bias[bbase + n0 + wn + f * 16 + lrow];

  constexpr float BS = 1.0f / (float)KS;
  #pragma unroll
  for (int i = 0; i < 8; ++i) {
    const int rbase = wm + i * 16 + (lane >> 4) * 4;
    #pragma unroll
    for (int jj = 0; jj < 4; ++jj) {
      int grow = m0 + rbase + jj;
      if (grow < Me) {
        #pragma unroll
        for (int j = 0; j < 4; ++j) {
          float v = acc_[i][j][jj] + bv[j] * BS;
          unsafeAtomicAdd(Of + (size_t)(tok0 + grow) * NDIM + n0 + wn + j * 16 + lrow, v);
        }
      }
    }
  }
}

extern "C" void kernel_launch(void* const* d_in, const int* in_sizes, int n_in,
                              void* d_out, int out_size, void* d_ws, size_t ws_size,
                              hipStream_t stream)
{
  const float* x  = (const float*)d_in[0];
  const float* W1 = (const float*)d_in[1];
  const float* b1 = (const float*)d_in[2];
  const float* W2 = (const float*)d_in[3];
  const float* b2 = (const float*)d_in[4];
  float* out = (float*)d_out;

  constexpr size_t H_BYTES   = (size_t)9536 * 4096 * 2;          // 78.1 MB
  constexpr size_t XB_BYTES  = (size_t)9536 * 1024 * 2;          // 19.5 MB
  unsigned short* h   = (unsigned short*)d_ws;
  unsigned short* xb  = (unsigned short*)((char*)d_ws + H_BYTES);
  unsigned short* w2b = (unsigned short*)((char*)d_ws + H_BYTES + XB_BYTES);
  // ws requirement 232 MB — proven available by R14's passing use_w2b path.

  // zero d_out for split-K atomic accumulation (~8 us)
  hipMemsetAsync(d_out, 0, (size_t)out_size * sizeof(float), stream);

  // x fp32 -> bf16 (58 MB traffic, ~10 us)
  cvt_bf16_kernel<<<2048, 256, 0, stream>>>(x, xb, 9536 * 1024 / 8);

  // G1 (624 blocks) + W2 conversion (640 blocks) fused: cvt rides G1's idle BW
  g1cvt<<<G1_NWG + CVT_NWG, 512, 0, stream>>>(xb, W1, b1, h, W2, w2b);

  // G2: 39 m x 4 n x KS4 = 624 blocks; NT = 4096/(4*32) = 32
  g2_gemm256b<1024, 4096, 624, 4><<<624, 512, 0, stream>>>(h, w2b, b2, out);
}